// Round 7
// baseline (519.803 us; speedup 1.0000x reference)
//
#include <hip/hip_runtime.h>
#include <hip/hip_fp16.h>
#include <hip/hip_cooperative_groups.h>

namespace cg = cooperative_groups;

// ---------------------------------------------------------------------------
// RelGraphConv (basis-decomposed, right-norm, sum over relations) on MI355X.
//
//   h[d] = B0^T * A0[d] + B1^T * A1[d] + x[d]@Wl + bias,  ReLU
//   A_b[d] = sum_{edges e->d} (coeff[r_e][b]/deg[r_e][d]) * x[src_e]
// R16: quarter-wave 16-edge predicated gather: 100us.
// R17/R18/R20: edge-centric stream / dual-node / lookback+cursor all
//   REGRESSED and were reverted. Lessons: (1) edges-in-flight-per-wave is
//   the gather objective; (2) serial atomic spin chains and value-returning
//   cursor atomics cost more than the deterministic rank/packed path.
// R19 (banked best, 285.7us): LDS-staged recs + quarter-wave-owns-node
//   gather (97us). Non-gather block ~185us vs ~65us roofline -> ~120us
//   unexplained (gaps or latency-bound pre kernels); never profiled (top-5
//   all gather_gemm).
// R21: SAME math as R19, but {memset,fused_pre,3 scans,fill} fused into ONE
//   cooperative kernel (grid.sync between phases; scan_mid replaced by
//   per-chunk self-summed base). 7 launches -> 2. Host falls back to the
//   exact R19 sequence if the coop launch fails. Diagnostic: pre_all will
//   appear in top-5 counters if it is the time sink.
// ---------------------------------------------------------------------------

#define DFEAT 128
#define NREL 8
#define ALDA 264   // LDS agg row stride in ushorts (256 data + 8 pad)
#define ECAP 1024  // staged-recs capacity (block edge count ~Poisson(384))

typedef __attribute__((ext_vector_type(8))) short bf16x8;
typedef __attribute__((ext_vector_type(4))) float f32x4;
typedef __attribute__((ext_vector_type(2))) float f32x2;

__device__ __forceinline__ ushort f2bf(float f) {
    unsigned u = __float_as_uint(f);
    u += 0x7FFF + ((u >> 16) & 1);          // round-to-nearest-even
    return (ushort)(u >> 16);
}
__device__ __forceinline__ float bflo(unsigned u) { return __uint_as_float(u << 16); }
__device__ __forceinline__ float bfhi(unsigned u) { return __uint_as_float(u & 0xFFFF0000u); }
__device__ __forceinline__ unsigned pack2bf(float lo, float hi) {
    return (unsigned)f2bf(lo) | ((unsigned)f2bf(hi) << 16);
}

// ---------------------------------------------------------------------------
// ONE cooperative kernel = zero-deg + count/rank + convert + w2T + scans +
// fill. Identical math/outputs to the R19 5-kernel pipeline.
// ---------------------------------------------------------------------------
__global__ __launch_bounds__(256, 2) void pre_all(
    const int* __restrict__ dst, const int* __restrict__ src,
    const float* __restrict__ coeff, const float* __restrict__ x,
    const float* __restrict__ bases, const float* __restrict__ loopw,
    int* __restrict__ deg, ushort* __restrict__ rank,
    unsigned* __restrict__ packed, int* __restrict__ rowStart,
    int* __restrict__ cnt, int* __restrict__ bsums,
    ushort* __restrict__ xb, ushort* __restrict__ w2T,
    uint2* __restrict__ recs,
    int RE, int E, int N, int n4, int NB) {
    cg::grid_group grid = cg::this_grid();
    __shared__ int sdata[256];
    const int tid = threadIdx.x;
    const int gstride = gridDim.x * blockDim.x;
    const int gt = blockIdx.x * blockDim.x + tid;

    // ---- phase 0: zero deg ----
    for (int i = gt; i < NREL * N; i += gstride) deg[i] = 0;
    grid.sync();

    // ---- phase 1: count+rank, convert x->xb, build w2T ----
    for (int i = gt; i < RE; i += gstride) {
        int r = i / E;
        int d = dst[i];
        rank[i] = (ushort)atomicAdd(&deg[r * N + d], 1);
    }
    for (int i = gt; i < n4; i += gstride) {
        float4 v = ((const float4*)x)[i];
        ushort4 o;
        o.x = f2bf(v.x); o.y = f2bf(v.y); o.z = f2bf(v.z); o.w = f2bf(v.w);
        ((ushort4*)xb)[i] = o;
    }
    for (int i = gt; i < 128 * 384; i += gstride) {
        int j = i / 384, k = i % 384;
        float v = (k < 256) ? bases[(k >> 7) * DFEAT * DFEAT + (k & 127) * DFEAT + j]
                            : loopw[(k - 256) * DFEAT + j];
        w2T[i] = f2bf(v);
    }
    grid.sync();

    // ---- phase 2: per-chunk sums (cnt + bsums) ----
    for (int b = blockIdx.x; b < NB; b += gridDim.x) {
        int idx = b * 256 + tid;
        int sum = 0;
        if (idx < N) {
            #pragma unroll
            for (int r = 0; r < NREL; ++r) sum += deg[r * N + idx];
            cnt[idx] = sum;
        }
        sdata[tid] = sum; __syncthreads();
        for (int s = 128; s > 0; s >>= 1) {
            if (tid < s) sdata[tid] += sdata[tid + s];
            __syncthreads();
        }
        if (tid == 0) bsums[b] = sdata[0];
        __syncthreads();
    }
    grid.sync();

    // ---- phase 3: per-chunk rowStart/packed (self-computed base) ----
    for (int b = blockIdx.x; b < NB; b += gridDim.x) {
        // base = sum bsums[0..b)  (bsums L2-hot, <=391 ints)
        int part = 0;
        for (int k = tid; k < b; k += 256) part += bsums[k];
        sdata[tid] = part; __syncthreads();
        for (int s = 128; s > 0; s >>= 1) {
            if (tid < s) sdata[tid] += sdata[tid + s];
            __syncthreads();
        }
        const int boff = sdata[0];
        __syncthreads();
        // local exclusive scan of cnt
        int idx = b * 256 + tid;
        int c = (idx < N) ? cnt[idx] : 0;
        sdata[tid] = c; __syncthreads();
        for (int off = 1; off < 256; off <<= 1) {
            int add = (tid >= off) ? sdata[tid - off] : 0;
            __syncthreads();
            sdata[tid] += add;
            __syncthreads();
        }
        const int excl = sdata[tid] - c;
        if (idx < N) {
            int rs = boff + excl;
            rowStart[idx] = rs;
            int pre = 0;
            #pragma unroll
            for (int r = 0; r < NREL; ++r) {
                int dv = deg[r * N + idx];
                packed[r * N + idx] = ((unsigned)(rs + pre) << 11) | (unsigned)dv;
                pre += dv;
            }
        }
        __syncthreads();
    }
    grid.sync();

    // ---- phase 4: fill recs ----
    for (int i = gt; i < RE; i += gstride) {
        int r = i / E;
        int d = dst[i];
        unsigned p = packed[r * N + d];
        int pos = (int)(p >> 11) + (int)rank[i];
        float inv = 1.0f / (float)(p & 2047u);
        __half2 hc = __floats2half2_rn(coeff[2 * r] * inv, coeff[2 * r + 1] * inv);
        uint2 rec;
        rec.x = (unsigned)src[i];
        rec.y = *(unsigned*)&hc;
        recs[pos] = rec;
    }
}

// ============================ R19 fallback path ============================
__global__ void fused_pre(const int* __restrict__ dst, int* __restrict__ deg,
                          ushort* __restrict__ rank,
                          const float* __restrict__ x, ushort* __restrict__ xb,
                          const float* __restrict__ bases, const float* __restrict__ loopw,
                          ushort* __restrict__ w2T,
                          int RE, int E, int N, int n4) {
    const int stride = gridDim.x * blockDim.x;
    const int t0 = blockIdx.x * blockDim.x + threadIdx.x;
    for (int i = t0; i < RE; i += stride) {
        int r = i / E;
        int d = dst[i];
        rank[i] = (ushort)atomicAdd(&deg[r * N + d], 1);
    }
    for (int i = t0; i < n4; i += stride) {
        float4 v = ((const float4*)x)[i];
        ushort4 o;
        o.x = f2bf(v.x); o.y = f2bf(v.y); o.z = f2bf(v.z); o.w = f2bf(v.w);
        ((ushort4*)xb)[i] = o;
    }
    for (int i = t0; i < 128 * 384; i += stride) {
        int j = i / 384, k = i % 384;
        float v = (k < 256) ? bases[(k >> 7) * DFEAT * DFEAT + (k & 127) * DFEAT + j]
                            : loopw[(k - 256) * DFEAT + j];
        w2T[i] = f2bf(v);
    }
}

__global__ void scan_block_sums(const int* __restrict__ deg, int* __restrict__ cnt,
                                int* __restrict__ bsums, int N) {
    __shared__ int sdata[256];
    int b = blockIdx.x, t = threadIdx.x;
    int idx = b * 256 + t;
    int sum = 0;
    if (idx < N) {
        #pragma unroll
        for (int r = 0; r < NREL; ++r) sum += deg[r * N + idx];
        cnt[idx] = sum;
    }
    sdata[t] = sum; __syncthreads();
    for (int s = 128; s > 0; s >>= 1) {
        if (t < s) sdata[t] += sdata[t + s];
        __syncthreads();
    }
    if (t == 0) bsums[b] = sdata[0];
}

__global__ void scan_mid(int* __restrict__ bsums, int nb) {
    __shared__ int s[256];
    int t = threadIdx.x;
    int base = t * 4;
    int v[4]; int sum = 0;
    #pragma unroll
    for (int i = 0; i < 4; ++i) {
        v[i] = sum;
        int c = (base + i < nb) ? bsums[base + i] : 0;
        sum += c;
    }
    s[t] = sum; __syncthreads();
    for (int off = 1; off < 256; off <<= 1) {
        int add = (t >= off) ? s[t - off] : 0;
        __syncthreads();
        s[t] += add;
        __syncthreads();
    }
    int excl = (t == 0) ? 0 : s[t - 1];
    #pragma unroll
    for (int i = 0; i < 4; ++i)
        if (base + i < nb) bsums[base + i] = excl + v[i];
}

__global__ void scan_write(const int* __restrict__ cnt, const int* __restrict__ bsums,
                           const int* __restrict__ deg,
                           int* __restrict__ rowStart, unsigned* __restrict__ packed,
                           int N) {
    __shared__ int tsum[256];
    int b = blockIdx.x, t = threadIdx.x;
    int idx = b * 256 + t;
    int c = (idx < N) ? cnt[idx] : 0;
    tsum[t] = c; __syncthreads();
    for (int off = 1; off < 256; off <<= 1) {
        int x = 0;
        if (t >= off) x = tsum[t - off];
        __syncthreads();
        if (t >= off) tsum[t] += x;
        __syncthreads();
    }
    int excl = (t == 0) ? 0 : tsum[t - 1];
    if (idx < N) {
        int rs = bsums[b] + excl;
        rowStart[idx] = rs;
        int pre = 0;
        #pragma unroll
        for (int r = 0; r < NREL; ++r) {
            int dv = deg[r * N + idx];
            packed[r * N + idx] = ((unsigned)(rs + pre) << 11) | (unsigned)dv;
            pre += dv;
        }
    }
}

__global__ void fill_kernel(const int* __restrict__ src, const int* __restrict__ dst,
                            const float* __restrict__ coeff,
                            const ushort* __restrict__ rank,
                            const unsigned* __restrict__ packed,
                            uint2* __restrict__ recs, int RE, int E, int N) {
    int idx = blockIdx.x * blockDim.x + threadIdx.x;
    if (idx >= RE) return;
    int r = idx / E;
    int d = dst[idx];
    unsigned p = packed[r * N + d];
    int pos = (int)(p >> 11) + (int)rank[idx];
    float inv = 1.0f / (float)(p & 2047u);
    __half2 hc = __floats2half2_rn(coeff[2 * r] * inv, coeff[2 * r + 1] * inv);
    uint2 rec;
    rec.x = (unsigned)src[idx];
    rec.y = *(unsigned*)&hc;
    recs[pos] = rec;
}
// ==========================================================================

// ---------------------------------------------------------------------------
// FUSED gather + GEMM (R19-exact, 97us). Block = 32 dst nodes, LDS 16.9KB
// agg + 8KB recs. Quarter-wave owns a node; 8-edge rounds, rec from LDS.
// ---------------------------------------------------------------------------
__global__ __launch_bounds__(256, 5) void gather_gemm(
    const uint2* __restrict__ recs, const int* __restrict__ rowStart,
    const ushort* __restrict__ xb,
    const ushort* __restrict__ w2T, const float* __restrict__ bias,
    float* __restrict__ out, int N, int RE) {
    __shared__ __align__(16) ushort agg[32 * ALDA];   // 16.9 KB
    __shared__ __align__(16) uint2 recsL[ECAP];       // 8 KB
    __shared__ int rsl[33];
    const int tid = threadIdx.x;
    const int wave = tid >> 6, lane = tid & 63;
    const int row0 = blockIdx.x * 32;

    // ---- phase 0: stage rowStarts + recs ----
    if (tid < 33) {
        int d = row0 + tid;
        rsl[tid] = (d < N) ? rowStart[d] : RE;
    }
    __syncthreads();
    const int e0 = rsl[0];
    const int cntE = rsl[32] - e0;
    const bool fits = (cntE <= ECAP);
    {
        const int lim = fits ? cntE : 0;
        for (int k = tid; k < lim; k += 256)
            recsL[k] = recs[e0 + k];
    }
    __syncthreads();

    // ---- phase 1: gather (quarter-wave per node) ----
    {
        const int qw = tid >> 4;        // quarter-wave id 0..15
        const int h  = tid & 15;        // feature slot: feats 8h..8h+7

        auto gatherNode = [&](int i, auto getRec) {
            const int s   = rsl[i] - e0;
            const int len = rsl[i + 1] - rsl[i];
            f32x2 A0 = {0.f,0.f}, A1 = {0.f,0.f}, A2 = {0.f,0.f}, A3 = {0.f,0.f};
            f32x2 B0 = {0.f,0.f}, B1 = {0.f,0.f}, B2 = {0.f,0.f}, B3 = {0.f,0.f};
            if (len > 0) {
                const int last = s + len - 1;
                for (int k = 0; k < len; k += 8) {
                    uint2 rc[8];
                    #pragma unroll
                    for (int j = 0; j < 8; ++j) {
                        int li = s + k + j;
                        rc[j] = getRec(li <= last ? li : last);
                    }
                    uint4 u[8];
                    #pragma unroll
                    for (int j = 0; j < 8; ++j)
                        u[j] = *(const uint4*)(xb + (size_t)rc[j].x * DFEAT + h * 8);
                    #pragma unroll
                    for (int j = 0; j < 8; ++j) {
                        bool v = (k + j) < len;
                        __half2 hc = *(__half2*)&rc[j].y;
                        float c0 = v ? __low2float(hc) : 0.f;
                        float c1 = v ? __high2float(hc) : 0.f;
                        f32x2 cc0 = {c0, c0}, cc1 = {c1, c1};
                        uint4 uu = u[j];
                        f32x2 f01 = {bflo(uu.x), bfhi(uu.x)};
                        f32x2 f23 = {bflo(uu.y), bfhi(uu.y)};
                        f32x2 f45 = {bflo(uu.z), bfhi(uu.z)};
                        f32x2 f67 = {bflo(uu.w), bfhi(uu.w)};
                        A0 += cc0 * f01; A1 += cc0 * f23; A2 += cc0 * f45; A3 += cc0 * f67;
                        B0 += cc1 * f01; B1 += cc1 * f23; B2 += cc1 * f45; B3 += cc1 * f67;
                    }
                }
            }
            uint4 w0, w1;
            w0.x = pack2bf(A0.x, A0.y); w0.y = pack2bf(A1.x, A1.y);
            w0.z = pack2bf(A2.x, A2.y); w0.w = pack2bf(A3.x, A3.y);
            w1.x = pack2bf(B0.x, B0.y); w1.y = pack2bf(B1.x, B1.y);
            w1.z = pack2bf(B2.x, B2.y); w1.w = pack2bf(B3.x, B3.y);
            *(uint4*)(agg + i * ALDA + h * 8)       = w0;   // c0 feats
            *(uint4*)(agg + i * ALDA + 128 + h * 8) = w1;   // c1 feats
        };

        if (fits) {
            #pragma unroll
            for (int p = 0; p < 2; ++p)
                gatherNode(qw + p * 16, [&](int li) { return recsL[li]; });
        } else {
            #pragma unroll
            for (int p = 0; p < 2; ++p)
                gatherNode(qw + p * 16, [&](int li) { return recs[e0 + li]; });
        }
    }
    __syncthreads();

    // ---- phase 2: GEMM (M=32) ----
    const int quad = lane >> 4, l16 = lane & 15;
    int arow[2];
    #pragma unroll
    for (int m = 0; m < 2; ++m) {
        int r = row0 + m * 16 + l16;
        arow[m] = (r < N) ? r : 0;
    }

    f32x4 zero = {0.f, 0.f, 0.f, 0.f};
    f32x4 acc[2][2] = {{zero, zero}, {zero, zero}};

    #pragma unroll
    for (int kt = 0; kt < 3; ++kt) {
        bf16x8 bq[4][2];
        #pragma unroll
        for (int t = 0; t < 4; ++t)
            #pragma unroll
            for (int g = 0; g < 2; ++g)
                bq[t][g] = *(const bf16x8*)(w2T + (size_t)(wave * 32 + g * 16 + l16) * 384
                                            + kt * 128 + t * 32 + quad * 8);
        #pragma unroll
        for (int m = 0; m < 2; ++m) {
            #pragma unroll
            for (int t = 0; t < 4; ++t) {
                bf16x8 a;
                if (kt < 2)
                    a = *(const bf16x8*)(agg + (m * 16 + l16) * ALDA + kt * 128 + t * 32 + quad * 8);
                else
                    a = *(const bf16x8*)(xb + (size_t)arow[m] * DFEAT + t * 32 + quad * 8);
                acc[m][0] = __builtin_amdgcn_mfma_f32_16x16x32_bf16(a, bq[t][0], acc[m][0], 0, 0, 0);
                acc[m][1] = __builtin_amdgcn_mfma_f32_16x16x32_bf16(a, bq[t][1], acc[m][1], 0, 0, 0);
            }
        }
    }

    #pragma unroll
    for (int g = 0; g < 2; ++g) {
        int c = wave * 32 + g * 16 + l16;
        float bv = bias[c];
        #pragma unroll
        for (int m = 0; m < 2; ++m) {
            #pragma unroll
            for (int reg = 0; reg < 4; ++reg) {
                int grow = row0 + m * 16 + quad * 4 + reg;
                if (grow < N)
                    out[(size_t)grow * DFEAT + c] = fmaxf(acc[m][g][reg] + bv, 0.f);
            }
        }
    }
}

extern "C" void kernel_launch(void* const* d_in, const int* in_sizes, int n_in,
                              void* d_out, int out_size, void* d_ws, size_t ws_size,
                              hipStream_t stream) {
    const float* x     = (const float*)d_in[0];
    const int*   src   = (const int*)  d_in[1];
    const int*   dst   = (const int*)  d_in[2];
    const float* coeff = (const float*)d_in[3];
    const float* bases = (const float*)d_in[4];
    const float* loopw = (const float*)d_in[5];
    const float* bias  = (const float*)d_in[6];
    float* out = (float*)d_out;

    const int N  = in_sizes[0] / DFEAT;            // 100000
    const int RE = in_sizes[1];                    // R*E = 1200000
    const int B  = in_sizes[4] / (DFEAT * DFEAT);  // 2
    const int R  = in_sizes[3] / B;                // 8
    const int E  = RE / R;                         // 150000
    const int NB = (N + 255) / 256;                // scan chunks (391)
    const int n4 = N * 32;

    // workspace layout (shared by both paths)
    char* ws = (char*)d_ws;
    size_t off = 0;
    auto alloc = [&](size_t bytes) { void* p = ws + off; off = (off + bytes + 255) & ~(size_t)255; return p; };
    int*      deg      = (int*)     alloc((size_t)R * N * sizeof(int));     // 3.2 MB
    ushort*   rank     = (ushort*)  alloc((size_t)RE * sizeof(ushort));     // 2.4 MB
    unsigned* packed   = (unsigned*)alloc((size_t)R * N * sizeof(unsigned));// 3.2 MB
    int*      cnt      = (int*)     alloc((size_t)N * sizeof(int));
    int*      rowStart = (int*)     alloc((size_t)N * sizeof(int));
    int*      bsums    = (int*)     alloc((size_t)NB * sizeof(int));
    ushort*   w2T      = (ushort*)  alloc((size_t)128 * 384 * sizeof(ushort));
    ushort*   xb       = (ushort*)  alloc((size_t)N * DFEAT * sizeof(ushort)); // 25.6 MB
    uint2*    recs     = (uint2*)   alloc((size_t)RE * sizeof(uint2));         // 9.6 MB

    // ---- try the single cooperative pre_all launch ----
    {
        void* args[] = {
            (void*)&dst, (void*)&src, (void*)&coeff, (void*)&x,
            (void*)&bases, (void*)&loopw,
            (void*)&deg, (void*)&rank, (void*)&packed, (void*)&rowStart,
            (void*)&cnt, (void*)&bsums, (void*)&xb, (void*)&w2T, (void*)&recs,
            (void*)&RE, (void*)&E, (void*)&N, (void*)&n4, (void*)&NB
        };
        hipError_t err = hipLaunchCooperativeKernel(
            (const void*)pre_all, dim3(512), dim3(256), args, 0, stream);
        if (err != hipSuccess) {
            (void)hipGetLastError();   // clear, fall back to R19 sequence
            hipMemsetAsync(deg, 0, (size_t)R * N * sizeof(int), stream);
            fused_pre<<<4096, 256, 0, stream>>>(dst, deg, rank, x, xb, bases,
                                                loopw, w2T, RE, E, N, n4);
            scan_block_sums<<<NB, 256, 0, stream>>>(deg, cnt, bsums, N);
            scan_mid<<<1, 256, 0, stream>>>(bsums, NB);
            scan_write<<<NB, 256, 0, stream>>>(cnt, bsums, deg, rowStart, packed, N);
            fill_kernel<<<(RE + 255) / 256, 256, 0, stream>>>(src, dst, coeff, rank,
                                                              packed, recs, RE, E, N);
        }
    }

    gather_gemm<<<(N + 31) / 32, 256, 0, stream>>>(recs, rowStart, xb, w2T,
                                                   bias, out, N, RE);
}

// Round 9
// 281.476 us; speedup vs baseline: 1.8467x; 1.8467x over previous
//
#include <hip/hip_runtime.h>
#include <hip/hip_fp16.h>

// ---------------------------------------------------------------------------
// RelGraphConv (basis-decomposed, right-norm, sum over relations) on MI355X.
//
//   h[d] = B0^T * A0[d] + B1^T * A1[d] + x[d]@Wl + bias,  ReLU
//   A_b[d] = sum_{edges e->d} (coeff[r_e][b]/deg[r_e][d]) * x[src_e]
// R16: quarter-wave 16-edge predicated gather: 100us.
// R17/R18/R20: edge-centric stream / dual-node / lookback+cursor all
//   REGRESSED -> reverted. Lessons: edges-in-flight-per-wave is the gather
//   objective; atomic spin chains and cursor atomics lose to rank/packed.
// R19 (banked best, 285.7us): LDS-staged recs + quarter-wave-owns-node
//   gather (97us, FETCH 148MB, occ 45%).
// R21: coop-fused pre at 512 blocks: correct but 23.7% occupancy, 317us.
//   Exposed recs scatter write-amplification (WRITE 111MB vs ~45 logical).
// R22: coop at 2048 blocks FAILED the capture: launch_bounds(256,2) caps
//   coop grid at 512; failing launch inside graph capture poisons it.
//   Cooperative path abandoned entirely.
// R23: exact R19 pipeline, minus scan_mid: scan_write self-computes its
//   chunk base by summing raw bsums[0..b) (<=391 L2-hot ints; logic proven
//   correct in R21 phase 3). 7 -> 6 dispatches. gather_gemm untouched.
// ---------------------------------------------------------------------------

#define DFEAT 128
#define NREL 8
#define ALDA 264   // LDS agg row stride in ushorts (256 data + 8 pad)
#define ECAP 1024  // staged-recs capacity (block edge count ~Poisson(384))

typedef __attribute__((ext_vector_type(8))) short bf16x8;
typedef __attribute__((ext_vector_type(4))) float f32x4;
typedef __attribute__((ext_vector_type(2))) float f32x2;

__device__ __forceinline__ ushort f2bf(float f) {
    unsigned u = __float_as_uint(f);
    u += 0x7FFF + ((u >> 16) & 1);          // round-to-nearest-even
    return (ushort)(u >> 16);
}
__device__ __forceinline__ float bflo(unsigned u) { return __uint_as_float(u << 16); }
__device__ __forceinline__ float bfhi(unsigned u) { return __uint_as_float(u & 0xFFFF0000u); }
__device__ __forceinline__ unsigned pack2bf(float lo, float hi) {
    return (unsigned)f2bf(lo) | ((unsigned)f2bf(hi) << 16);
}

// Fused: count_rank (atomic-latency-bound) + convert_x + build_w2T (BW-bound).
// deg must be pre-zeroed. w2T[j][k]: k<256 -> bases[k>>7][k&127][j],
// else loopw[k-256][j].
__global__ void fused_pre(const int* __restrict__ dst, int* __restrict__ deg,
                          ushort* __restrict__ rank,
                          const float* __restrict__ x, ushort* __restrict__ xb,
                          const float* __restrict__ bases, const float* __restrict__ loopw,
                          ushort* __restrict__ w2T,
                          int RE, int E, int N, int n4) {
    const int stride = gridDim.x * blockDim.x;
    const int t0 = blockIdx.x * blockDim.x + threadIdx.x;
    for (int i = t0; i < RE; i += stride) {
        int r = i / E;
        int d = dst[i];
        rank[i] = (ushort)atomicAdd(&deg[r * N + d], 1);
    }
    for (int i = t0; i < n4; i += stride) {
        float4 v = ((const float4*)x)[i];
        ushort4 o;
        o.x = f2bf(v.x); o.y = f2bf(v.y); o.z = f2bf(v.z); o.w = f2bf(v.w);
        ((ushort4*)xb)[i] = o;
    }
    for (int i = t0; i < 128 * 384; i += stride) {
        int j = i / 384, k = i % 384;
        float v = (k < 256) ? bases[(k >> 7) * DFEAT * DFEAT + (k & 127) * DFEAT + j]
                            : loopw[(k - 256) * DFEAT + j];
        w2T[i] = f2bf(v);
    }
}

// Per 256-node chunk: cnt[d] = sum_r deg[r][d]; bsums[b] = chunk total (raw).
__global__ void scan_block_sums(const int* __restrict__ deg, int* __restrict__ cnt,
                                int* __restrict__ bsums, int N) {
    __shared__ int sdata[256];
    int b = blockIdx.x, t = threadIdx.x;
    int idx = b * 256 + t;
    int sum = 0;
    if (idx < N) {
        #pragma unroll
        for (int r = 0; r < NREL; ++r) sum += deg[r * N + idx];
        cnt[idx] = sum;
    }
    sdata[t] = sum; __syncthreads();
    for (int s = 128; s > 0; s >>= 1) {
        if (t < s) sdata[t] += sdata[t + s];
        __syncthreads();
    }
    if (t == 0) bsums[b] = sdata[0];
}

// rowStart[d] + packed[r*N+d] = ((rowStart[d]+prefix_r)<<11)|deg_rd.
// R23: self-computes chunk base = sum bsums[0..b) (raw, L2-hot, <=391 ints)
// -> scan_mid launch eliminated. Logic hardware-proven in R21 phase 3.
__global__ void scan_write(const int* __restrict__ cnt, const int* __restrict__ bsums,
                           const int* __restrict__ deg,
                           int* __restrict__ rowStart, unsigned* __restrict__ packed,
                           int N) {
    __shared__ int sdata[256];
    int b = blockIdx.x, t = threadIdx.x;

    // chunk base: sum of raw bsums[0..b)
    int part = 0;
    for (int k = t; k < b; k += 256) part += bsums[k];
    sdata[t] = part; __syncthreads();
    for (int s = 128; s > 0; s >>= 1) {
        if (t < s) sdata[t] += sdata[t + s];
        __syncthreads();
    }
    const int boff = sdata[0];
    __syncthreads();

    // local exclusive scan of cnt
    int idx = b * 256 + t;
    int c = (idx < N) ? cnt[idx] : 0;
    sdata[t] = c; __syncthreads();
    for (int off = 1; off < 256; off <<= 1) {
        int x = 0;
        if (t >= off) x = sdata[t - off];
        __syncthreads();
        if (t >= off) sdata[t] += x;
        __syncthreads();
    }
    int excl = sdata[t] - c;
    if (idx < N) {
        int rs = boff + excl;
        rowStart[idx] = rs;
        int pre = 0;
        #pragma unroll
        for (int r = 0; r < NREL; ++r) {
            int dv = deg[r * N + idx];
            packed[r * N + idx] = ((unsigned)(rs + pre) << 11) | (unsigned)dv;
            pre += dv;
        }
    }
}

// Atomic-free placement: pos = (packed>>11) + rank. ONE random read per edge.
__global__ void fill_kernel(const int* __restrict__ src, const int* __restrict__ dst,
                            const float* __restrict__ coeff,
                            const ushort* __restrict__ rank,
                            const unsigned* __restrict__ packed,
                            uint2* __restrict__ recs, int RE, int E, int N) {
    int idx = blockIdx.x * blockDim.x + threadIdx.x;
    if (idx >= RE) return;
    int r = idx / E;
    int d = dst[idx];
    unsigned p = packed[r * N + d];
    int pos = (int)(p >> 11) + (int)rank[idx];
    float inv = 1.0f / (float)(p & 2047u);
    __half2 hc = __floats2half2_rn(coeff[2 * r] * inv, coeff[2 * r + 1] * inv);
    uint2 rec;
    rec.x = (unsigned)src[idx];
    rec.y = *(unsigned*)&hc;
    recs[pos] = rec;
}

// ---------------------------------------------------------------------------
// FUSED gather + GEMM (R19-exact, 97us). Block = 32 dst nodes, LDS 16.9KB
// agg + 8KB recs. Quarter-wave owns a node; 8-edge rounds, rec from LDS.
// ---------------------------------------------------------------------------
__global__ __launch_bounds__(256, 5) void gather_gemm(
    const uint2* __restrict__ recs, const int* __restrict__ rowStart,
    const ushort* __restrict__ xb,
    const ushort* __restrict__ w2T, const float* __restrict__ bias,
    float* __restrict__ out, int N, int RE) {
    __shared__ __align__(16) ushort agg[32 * ALDA];   // 16.9 KB
    __shared__ __align__(16) uint2 recsL[ECAP];       // 8 KB
    __shared__ int rsl[33];
    const int tid = threadIdx.x;
    const int wave = tid >> 6, lane = tid & 63;
    const int row0 = blockIdx.x * 32;

    // ---- phase 0: stage rowStarts + recs ----
    if (tid < 33) {
        int d = row0 + tid;
        rsl[tid] = (d < N) ? rowStart[d] : RE;
    }
    __syncthreads();
    const int e0 = rsl[0];
    const int cntE = rsl[32] - e0;
    const bool fits = (cntE <= ECAP);
    {
        const int lim = fits ? cntE : 0;
        for (int k = tid; k < lim; k += 256)
            recsL[k] = recs[e0 + k];
    }
    __syncthreads();

    // ---- phase 1: gather (quarter-wave per node) ----
    {
        const int qw = tid >> 4;        // quarter-wave id 0..15
        const int h  = tid & 15;        // feature slot: feats 8h..8h+7

        auto gatherNode = [&](int i, auto getRec) {
            const int s   = rsl[i] - e0;
            const int len = rsl[i + 1] - rsl[i];
            f32x2 A0 = {0.f,0.f}, A1 = {0.f,0.f}, A2 = {0.f,0.f}, A3 = {0.f,0.f};
            f32x2 B0 = {0.f,0.f}, B1 = {0.f,0.f}, B2 = {0.f,0.f}, B3 = {0.f,0.f};
            if (len > 0) {
                const int last = s + len - 1;
                for (int k = 0; k < len; k += 8) {
                    uint2 rc[8];
                    #pragma unroll
                    for (int j = 0; j < 8; ++j) {
                        int li = s + k + j;
                        rc[j] = getRec(li <= last ? li : last);
                    }
                    uint4 u[8];
                    #pragma unroll
                    for (int j = 0; j < 8; ++j)
                        u[j] = *(const uint4*)(xb + (size_t)rc[j].x * DFEAT + h * 8);
                    #pragma unroll
                    for (int j = 0; j < 8; ++j) {
                        bool v = (k + j) < len;
                        __half2 hc = *(__half2*)&rc[j].y;
                        float c0 = v ? __low2float(hc) : 0.f;
                        float c1 = v ? __high2float(hc) : 0.f;
                        f32x2 cc0 = {c0, c0}, cc1 = {c1, c1};
                        uint4 uu = u[j];
                        f32x2 f01 = {bflo(uu.x), bfhi(uu.x)};
                        f32x2 f23 = {bflo(uu.y), bfhi(uu.y)};
                        f32x2 f45 = {bflo(uu.z), bfhi(uu.z)};
                        f32x2 f67 = {bflo(uu.w), bfhi(uu.w)};
                        A0 += cc0 * f01; A1 += cc0 * f23; A2 += cc0 * f45; A3 += cc0 * f67;
                        B0 += cc1 * f01; B1 += cc1 * f23; B2 += cc1 * f45; B3 += cc1 * f67;
                    }
                }
            }
            uint4 w0, w1;
            w0.x = pack2bf(A0.x, A0.y); w0.y = pack2bf(A1.x, A1.y);
            w0.z = pack2bf(A2.x, A2.y); w0.w = pack2bf(A3.x, A3.y);
            w1.x = pack2bf(B0.x, B0.y); w1.y = pack2bf(B1.x, B1.y);
            w1.z = pack2bf(B2.x, B2.y); w1.w = pack2bf(B3.x, B3.y);
            *(uint4*)(agg + i * ALDA + h * 8)       = w0;   // c0 feats
            *(uint4*)(agg + i * ALDA + 128 + h * 8) = w1;   // c1 feats
        };

        if (fits) {
            #pragma unroll
            for (int p = 0; p < 2; ++p)
                gatherNode(qw + p * 16, [&](int li) { return recsL[li]; });
        } else {
            #pragma unroll
            for (int p = 0; p < 2; ++p)
                gatherNode(qw + p * 16, [&](int li) { return recs[e0 + li]; });
        }
    }
    __syncthreads();

    // ---- phase 2: GEMM (M=32) ----
    const int quad = lane >> 4, l16 = lane & 15;
    int arow[2];
    #pragma unroll
    for (int m = 0; m < 2; ++m) {
        int r = row0 + m * 16 + l16;
        arow[m] = (r < N) ? r : 0;
    }

    f32x4 zero = {0.f, 0.f, 0.f, 0.f};
    f32x4 acc[2][2] = {{zero, zero}, {zero, zero}};

    #pragma unroll
    for (int kt = 0; kt < 3; ++kt) {
        bf16x8 bq[4][2];
        #pragma unroll
        for (int t = 0; t < 4; ++t)
            #pragma unroll
            for (int g = 0; g < 2; ++g)
                bq[t][g] = *(const bf16x8*)(w2T + (size_t)(wave * 32 + g * 16 + l16) * 384
                                            + kt * 128 + t * 32 + quad * 8);
        #pragma unroll
        for (int m = 0; m < 2; ++m) {
            #pragma unroll
            for (int t = 0; t < 4; ++t) {
                bf16x8 a;
                if (kt < 2)
                    a = *(const bf16x8*)(agg + (m * 16 + l16) * ALDA + kt * 128 + t * 32 + quad * 8);
                else
                    a = *(const bf16x8*)(xb + (size_t)arow[m] * DFEAT + t * 32 + quad * 8);
                acc[m][0] = __builtin_amdgcn_mfma_f32_16x16x32_bf16(a, bq[t][0], acc[m][0], 0, 0, 0);
                acc[m][1] = __builtin_amdgcn_mfma_f32_16x16x32_bf16(a, bq[t][1], acc[m][1], 0, 0, 0);
            }
        }
    }

    #pragma unroll
    for (int g = 0; g < 2; ++g) {
        int c = wave * 32 + g * 16 + l16;
        float bv = bias[c];
        #pragma unroll
        for (int m = 0; m < 2; ++m) {
            #pragma unroll
            for (int reg = 0; reg < 4; ++reg) {
                int grow = row0 + m * 16 + quad * 4 + reg;
                if (grow < N)
                    out[(size_t)grow * DFEAT + c] = fmaxf(acc[m][g][reg] + bv, 0.f);
            }
        }
    }
}

extern "C" void kernel_launch(void* const* d_in, const int* in_sizes, int n_in,
                              void* d_out, int out_size, void* d_ws, size_t ws_size,
                              hipStream_t stream) {
    const float* x     = (const float*)d_in[0];
    const int*   src   = (const int*)  d_in[1];
    const int*   dst   = (const int*)  d_in[2];
    const float* coeff = (const float*)d_in[3];
    const float* bases = (const float*)d_in[4];
    const float* loopw = (const float*)d_in[5];
    const float* bias  = (const float*)d_in[6];
    float* out = (float*)d_out;

    const int N  = in_sizes[0] / DFEAT;            // 100000
    const int RE = in_sizes[1];                    // R*E = 1200000
    const int B  = in_sizes[4] / (DFEAT * DFEAT);  // 2
    const int R  = in_sizes[3] / B;                // 8
    const int E  = RE / R;                         // 150000
    const int NB = (N + 255) / 256;                // scan chunks (391)
    const int n4 = N * 32;

    // workspace layout
    char* ws = (char*)d_ws;
    size_t off = 0;
    auto alloc = [&](size_t bytes) { void* p = ws + off; off = (off + bytes + 255) & ~(size_t)255; return p; };
    int*      deg      = (int*)     alloc((size_t)R * N * sizeof(int));     // 3.2 MB
    ushort*   rank     = (ushort*)  alloc((size_t)RE * sizeof(ushort));     // 2.4 MB
    unsigned* packed   = (unsigned*)alloc((size_t)R * N * sizeof(unsigned));// 3.2 MB
    int*      cnt      = (int*)     alloc((size_t)N * sizeof(int));
    int*      rowStart = (int*)     alloc((size_t)N * sizeof(int));
    int*      bsums    = (int*)     alloc((size_t)NB * sizeof(int));
    ushort*   w2T      = (ushort*)  alloc((size_t)128 * 384 * sizeof(ushort));
    ushort*   xb       = (ushort*)  alloc((size_t)N * DFEAT * sizeof(ushort)); // 25.6 MB
    uint2*    recs     = (uint2*)   alloc((size_t)RE * sizeof(uint2));         // 9.6 MB

    hipMemsetAsync(deg, 0, (size_t)R * N * sizeof(int), stream);
    fused_pre<<<4096, 256, 0, stream>>>(dst, deg, rank, x, xb, bases, loopw, w2T,
                                        RE, E, N, n4);
    scan_block_sums<<<NB, 256, 0, stream>>>(deg, cnt, bsums, N);
    scan_write<<<NB, 256, 0, stream>>>(cnt, bsums, deg, rowStart, packed, N);
    fill_kernel<<<(RE + 255) / 256, 256, 0, stream>>>(src, dst, coeff, rank, packed,
                                                      recs, RE, E, N);
    gather_gemm<<<(N + 31) / 32, 256, 0, stream>>>(recs, rowStart, xb, w2T,
                                                   bias, out, N, RE);
}